// Round 12
// baseline (453.705 us; speedup 1.0000x reference)
//
#include <hip/hip_runtime.h>
#include <stdint.h>

// ---------------------------------------------------------------------------
// CrossAttentionRope: x(16,256,768), ctx(16,4096,768) f32 -> out(16,256,768) f32
// R12: R8 base; KV GEMMs get T4 counted-vmcnt software pipeline:
//      double-buffered LDS, gld_lds w16 + pre-swizzled source (R11-proven),
//      raw s_barrier (no vmcnt(0) drain), vmcnt(8) per tile — loads span
//      barriers. Tile/waves/read-formulas/epilogues verbatim R8.
//      cvt/twt/Q/O/attn verbatim R8.
// ---------------------------------------------------------------------------

typedef __bf16 bf16x8 __attribute__((ext_vector_type(8)));
typedef unsigned short u16x8 __attribute__((ext_vector_type(8)));
typedef unsigned short u16x4 __attribute__((ext_vector_type(4)));
typedef uint32_t u32x4 __attribute__((ext_vector_type(4)));
typedef float f32x4 __attribute__((ext_vector_type(4)));

#define DIMF 768
#define NHEAD 12
#define NKV 4096
#define NQ 256
#define NB 16

struct alignas(8) us4 { unsigned short x, y, z, w; };

__device__ __forceinline__ unsigned short f2bf(float x) {
  uint32_t u = __float_as_uint(x);
  u += 0x7fffu + ((u >> 16) & 1u);   // round-to-nearest-even
  return (unsigned short)(u >> 16);
}

__device__ __forceinline__ uint32_t cvtpk(float a, float b) {
  uint32_t r;
  asm("v_cvt_pk_bf16_f32 %0, %1, %2" : "=v"(r) : "v"(a), "v"(b));
  return r;
}

__device__ __forceinline__ void gld_lds16(const unsigned short* g, unsigned short* l) {
  __builtin_amdgcn_global_load_lds(
      (const __attribute__((address_space(1))) uint32_t*)(uintptr_t)g,
      (__attribute__((address_space(3))) uint32_t*)(uintptr_t)l, 16, 0, 0);
}

// ---------------- convert f32 -> bf16 (vectorized, grid-stride) ------------
__global__ void cvt_kernel(const float* __restrict__ in, unsigned short* __restrict__ out, int n) {
  int stride = gridDim.x * blockDim.x * 4;
  for (int i = (blockIdx.x * blockDim.x + threadIdx.x) * 4; i < n; i += stride) {
    float4 v = *(const float4*)(in + i);
    us4 o{f2bf(v.x), f2bf(v.y), f2bf(v.z), f2bf(v.w)};
    *(us4*)(out + i) = o;
  }
}

// ---------------- weight transpose + cvt: Wt[n][k] = W[k][n] ---------------
__global__ void twt_kernel(const float* __restrict__ W0, const float* __restrict__ W1,
                           const float* __restrict__ W2, const float* __restrict__ W3,
                           unsigned short* __restrict__ O0, unsigned short* __restrict__ O1,
                           unsigned short* __restrict__ O2, unsigned short* __restrict__ O3) {
  const float* W; unsigned short* O;
  switch (blockIdx.z) {
    case 0: W = W0; O = O0; break;
    case 1: W = W1; O = O1; break;
    case 2: W = W2; O = O2; break;
    default: W = W3; O = O3; break;
  }
  __shared__ float t[32][33];
  int x0 = blockIdx.x * 32, y0 = blockIdx.y * 32;
  int tx = threadIdx.x, ty = threadIdx.y;
#pragma unroll
  for (int j = 0; j < 4; ++j)
    t[ty + 8 * j][tx] = W[(size_t)(y0 + ty + 8 * j) * DIMF + x0 + tx];
  __syncthreads();
#pragma unroll
  for (int j = 0; j < 4; ++j)
    O[(size_t)(x0 + ty + 8 * j) * DIMF + y0 + tx] = f2bf(t[tx][ty + 8 * j]);
}

// ---------------- KV GEMM: T4 counted-vmcnt pipeline, 128x128, 4 waves ------
// MODE 0: K-proj (+rope_k) -> K [b][h][n][64]; MODE 1: V-proj -> Vt.
// Double-buffered LDS; tile t body: vmcnt(8) [t landed, t+1 in flight] ->
// raw barrier -> compute -> raw barrier -> issue stage(t+2) into freed buf.
template <int MODE>
__launch_bounds__(256, 2)
__global__ void kvpipe_kernel(const unsigned short* __restrict__ A,
                              const unsigned short* __restrict__ Bt,
                              void* __restrict__ outp,
                              const float* __restrict__ rope) {
  __shared__ unsigned short As[2][128 * 64];   // 32KB
  __shared__ unsigned short Bs[2][128 * 64];   // 32KB
  const int t = threadIdx.x;
  const int lane = t & 63, wid = t >> 6;
  const int g = lane >> 4, lc = lane & 15;
  const int wr = wid >> 1, wc = wid & 1;

  // R8-proven XCD col-fast swizzle (3072 % 8 == 0 -> bijective)
  const int swz = (blockIdx.x & 7) * 384 + (blockIdx.x >> 3);
  const int rowBase = (swz / 6) * 128;
  const int colBase = (swz % 6) * 128;

  const f32x4 z4 = {0.f, 0.f, 0.f, 0.f};
  f32x4 acc[4][4];
#pragma unroll
  for (int m = 0; m < 4; ++m)
#pragma unroll
    for (int n = 0; n < 4; ++n) acc[m][n] = z4;

  // staging map (R6/R11-proven): lane -> row l>>3 in 8-row group, source
  // chunk pre-XOR'd (l&7)^(l>>3); LDS dest linear => LDS[row][slot s] holds
  // global chunk s^(row&7), matching the R8 XOR'd read formula.
  const int sr = lane >> 3;
  const int sc = (lane & 7) ^ sr;
  const unsigned short* Abase = A + (size_t)(rowBase + wid * 32 + sr) * DIMF + sc * 8;
  const unsigned short* Bbase = Bt + (size_t)(colBase + wid * 32 + sr) * DIMF + sc * 8;

#define STAGE(KB, BUF)                                                                     \
  do {                                                                                     \
    _Pragma("unroll")                                                                      \
    for (int i = 0; i < 4; ++i) {                                                          \
      gld_lds16(Abase + (size_t)(i * 8) * DIMF + (KB) * 64, &As[BUF][(wid * 32 + i * 8) * 64]); \
      gld_lds16(Bbase + (size_t)(i * 8) * DIMF + (KB) * 64, &Bs[BUF][(wid * 32 + i * 8) * 64]); \
    }                                                                                      \
  } while (0)

  STAGE(0, 0);
  STAGE(1, 1);

#pragma unroll
  for (int kb = 0; kb < 12; ++kb) {
    const int c = kb & 1;
    // counted wait: tile kb's 8 loads retired; tile kb+1's 8 may stay in
    // flight (T4: never drain to 0 mid-loop). Last tile: full drain.
    if (kb < 11) {
      asm volatile("s_waitcnt vmcnt(8)" ::: "memory");
    } else {
      asm volatile("s_waitcnt vmcnt(0)" ::: "memory");
    }
    __builtin_amdgcn_s_barrier();          // all waves' tile-kb loads landed
    asm volatile("" ::: "memory");         // compiler fence: no hoisted reads
#pragma unroll
    for (int kk = 0; kk < 2; ++kk) {
      bf16x8 af[4], bfr[4];
#pragma unroll
      for (int m = 0; m < 4; ++m) {
        int row = wr * 64 + m * 16 + lc;
        af[m] = *(const bf16x8*)&As[c][row * 64 + (((kk * 4 + g) ^ (row & 7)) << 3)];
      }
#pragma unroll
      for (int n = 0; n < 4; ++n) {
        int row = wc * 64 + n * 16 + lc;
        bfr[n] = *(const bf16x8*)&Bs[c][row * 64 + (((kk * 4 + g) ^ (row & 7)) << 3)];
      }
#pragma unroll
      for (int m = 0; m < 4; ++m)
#pragma unroll
        for (int n = 0; n < 4; ++n)
          acc[m][n] = __builtin_amdgcn_mfma_f32_16x16x32_bf16(af[m], bfr[n], acc[m][n], 0, 0, 0);
    }
    asm volatile("" ::: "memory");         // compiler fence: no sunk reads
    __builtin_amdgcn_s_barrier();          // all waves done reading buf c
    if (kb + 2 < 12) STAGE(kb + 2, c);     // refill freed buffer, don't wait
  }
#undef STAGE

  // ---- epilogue (R8 verbatim; C/D: col=lc, row=g*4+r) ----
  if (MODE == 0) {
    unsigned short* Ko = (unsigned short*)outp;
#pragma unroll
    for (int m = 0; m < 4; ++m)
#pragma unroll
      for (int n = 0; n < 4; ++n)
#pragma unroll
        for (int r = 0; r < 4; ++r) {
          int p = rowBase + wr * 64 + m * 16 + g * 4 + r;
          int f = colBase + wc * 64 + n * 16 + lc;
          int d = f & 63, h = f >> 6;
          float v = acc[m][n][r];
          float vo = __shfl_xor(v, 1);
          int b = p >> 12, nkv = p & 4095;
          float sn = rope[nkv * 128 + d], cs = rope[nkv * 128 + 64 + d];
          float o = (d & 1) ? fmaf(vo, sn, v * cs) : fmaf(-vo, sn, v * cs);
          Ko[((size_t)(b * NHEAD + h) * NKV + nkv) * 64 + d] = f2bf(o);
        }
  } else {
    unsigned short* Vt = (unsigned short*)outp;
#pragma unroll
    for (int m = 0; m < 4; ++m)
#pragma unroll
      for (int n = 0; n < 4; ++n) {
        int p0 = rowBase + wr * 64 + m * 16 + g * 4;
        int b = p0 >> 12, nkv0 = p0 & 4095;
        int f = colBase + wc * 64 + n * 16 + lc;
        int d = f & 63, h = f >> 6;
        us4 wv{f2bf(acc[m][n][0]), f2bf(acc[m][n][1]), f2bf(acc[m][n][2]), f2bf(acc[m][n][3])};
        *(us4*)&Vt[((size_t)(b * NHEAD + h) * 64 + d) * NKV + nkv0] = wv;
      }
  }
}

// ---------------- GEMM (R5/R8-proven reg-staged): Q-proj / O-proj -----------
// MODE 2: Q-proj (+rope_q, *0.125) -> Q [b][h][nq][64] bf16  [2D grid]
// MODE 3: O-proj -> out f32 [p][768]                          [2D grid]
template <int MODE>
__launch_bounds__(256, 2)
__global__ void gemm_kernel(const unsigned short* __restrict__ A,
                            const unsigned short* __restrict__ Bt,
                            void* __restrict__ outp,
                            const float* __restrict__ rope) {
  __shared__ unsigned short As[128 * 64];
  __shared__ unsigned short Bs[128 * 64];
  const int t = threadIdx.x;
  const int lane = t & 63, wid = t >> 6;
  const int g = lane >> 4, lc = lane & 15;
  const int wr = wid >> 1, wc = wid & 1;
  const int rowBase = blockIdx.x * 128, colBase = blockIdx.y * 128;

  const f32x4 z4 = {0.f, 0.f, 0.f, 0.f};
  f32x4 acc[4][4];
#pragma unroll
  for (int m = 0; m < 4; ++m)
#pragma unroll
    for (int n = 0; n < 4; ++n) acc[m][n] = z4;

  const int r0 = t >> 3;
  const int c0 = t & 7;

  bf16x8 ra[4], rbx[4];
#pragma unroll
  for (int pp = 0; pp < 4; ++pp) {
    int row = pp * 32 + r0;
    ra[pp] = *(const bf16x8*)(A + (size_t)(rowBase + row) * DIMF + c0 * 8);
    rbx[pp] = *(const bf16x8*)(Bt + (size_t)(colBase + row) * DIMF + c0 * 8);
  }

  for (int kb = 0; kb < 12; ++kb) {
    __syncthreads();
#pragma unroll
    for (int pp = 0; pp < 4; ++pp) {
      int row = pp * 32 + r0;
      int ph = ((c0 ^ (row & 7)) << 3);
      *(bf16x8*)&As[row * 64 + ph] = ra[pp];
      *(bf16x8*)&Bs[row * 64 + ph] = rbx[pp];
    }
    __syncthreads();
    if (kb + 1 < 12) {
      int kn = (kb + 1) * 64;
#pragma unroll
      for (int pp = 0; pp < 4; ++pp) {
        int row = pp * 32 + r0;
        ra[pp] = *(const bf16x8*)(A + (size_t)(rowBase + row) * DIMF + kn + c0 * 8);
        rbx[pp] = *(const bf16x8*)(Bt + (size_t)(colBase + row) * DIMF + kn + c0 * 8);
      }
    }
#pragma unroll
    for (int kk = 0; kk < 2; ++kk) {
      bf16x8 af[4], bfr[4];
#pragma unroll
      for (int m = 0; m < 4; ++m) {
        int row = wr * 64 + m * 16 + lc;
        int ch = kk * 4 + g;
        af[m] = *(const bf16x8*)&As[row * 64 + (((ch ^ (row & 7))) << 3)];
      }
#pragma unroll
      for (int n = 0; n < 4; ++n) {
        int row = wc * 64 + n * 16 + lc;
        int ch = kk * 4 + g;
        bfr[n] = *(const bf16x8*)&Bs[row * 64 + (((ch ^ (row & 7))) << 3)];
      }
#pragma unroll
      for (int m = 0; m < 4; ++m)
#pragma unroll
        for (int n = 0; n < 4; ++n)
          acc[m][n] = __builtin_amdgcn_mfma_f32_16x16x32_bf16(af[m], bfr[n], acc[m][n], 0, 0, 0);
    }
  }

  if (MODE == 2) {
    unsigned short* Ko = (unsigned short*)outp;
#pragma unroll
    for (int m = 0; m < 4; ++m)
#pragma unroll
      for (int n = 0; n < 4; ++n)
#pragma unroll
        for (int r = 0; r < 4; ++r) {
          int p = rowBase + wr * 64 + m * 16 + g * 4 + r;
          int f = colBase + wc * 64 + n * 16 + lc;
          int d = f & 63, h = f >> 6;
          float v = acc[m][n][r];
          float vo = __shfl_xor(v, 1);
          int b = p >> 8, nq = p & 255;
          float sn = rope[nq * 128 + d], cs = rope[nq * 128 + 64 + d];
          float o = (d & 1) ? fmaf(vo, sn, v * cs) : fmaf(-vo, sn, v * cs);
          Ko[((size_t)(b * NHEAD + h) * NQ + nq) * 64 + d] = f2bf(o * 0.125f);
        }
  } else {
    float* Co = (float*)outp;
#pragma unroll
    for (int m = 0; m < 4; ++m)
#pragma unroll
      for (int n = 0; n < 4; ++n)
#pragma unroll
        for (int r = 0; r < 4; ++r) {
          int p = rowBase + wr * 64 + m * 16 + g * 4 + r;
          int f = colBase + wc * 64 + n * 16 + lc;
          Co[(size_t)p * DIMF + f] = acc[m][n][r];
        }
  }
}

// ---------------- flash attention (R5-proven, verbatim) --------------------
__launch_bounds__(256, 2)
__global__ void attn_kernel(const unsigned short* __restrict__ Qb,
                            const unsigned short* __restrict__ Kb,
                            const unsigned short* __restrict__ Vtb,
                            unsigned short* __restrict__ Ob) {
  __shared__ unsigned short Ks[128 * 64];    // [kv][d]  16KB, chunk ^= (kv&7)
  __shared__ unsigned short Vts[64 * 128];   // [d][kv'] 16KB, chunk ^= (d&15)
  const int logical = (blockIdx.x & 7) * 96 + (blockIdx.x >> 3);  // 768%8==0
  const int qt = logical & 3, bh = logical >> 2;
  const int b = bh / NHEAD, h = bh % NHEAD;
  const int t = threadIdx.x;
  const int lane = t & 63, w = t >> 6;
  const int g = lane >> 4, lc = lane & 15;
  const int qrow = qt * 64 + w * 16 + lc;

  bf16x8 qf[2];
#pragma unroll
  for (int kk = 0; kk < 2; ++kk)
    qf[kk] = *(const bf16x8*)(Qb + ((size_t)bh * NQ + qrow) * 64 + kk * 32 + g * 8);

  const f32x4 z4 = {0.f, 0.f, 0.f, 0.f};
  f32x4 oacc[4];
#pragma unroll
  for (int df = 0; df < 4; ++df) oacc[df] = z4;
  float mrun = -1e30f, lrun = 0.f;

  const int r0 = t >> 3, c0 = t & 7;
  const int d0 = t >> 4, cv = t & 15;
  const int pbase = 32 * (cv >> 2) + 16 * (cv & 1) + 4 * ((cv >> 1) & 1);
  const int ch0 = pbase >> 3, of0 = pbase & 7;
  const int ch1 = (pbase + 8) >> 3;

  u16x8 rk[4], rv[4];
#define LOAD_TILE(KT)                                                                        \
  do {                                                                                       \
    const int kvb = (KT) * 128;                                                              \
    _Pragma("unroll")                                                                        \
    for (int pp = 0; pp < 4; ++pp)                                                           \
      rk[pp] = *(const u16x8*)(Kb + ((size_t)bh * NKV + kvb + pp * 32 + r0) * 64 + c0 * 8);  \
    _Pragma("unroll")                                                                        \
    for (int pp = 0; pp < 4; ++pp)                                                           \
      rv[pp] = *(const u16x8*)(Vtb + ((size_t)bh * 64 + pp * 16 + d0) * NKV + kvb + cv * 8); \
  } while (0)

  LOAD_TILE(0);

  for (int kt = 0; kt < 32; ++kt) {
    __syncthreads();
#pragma unroll
    for (int pp = 0; pp < 4; ++pp) {
      int row = pp * 32 + r0;
      *(u16x8*)&Ks[row * 64 + ((c0 ^ (row & 7)) << 3)] = rk[pp];
    }
#pragma unroll
    for (int pp = 0; pp < 4; ++pp) {
      int d = pp * 16 + d0;
      u16x4 lo = __builtin_shufflevector(rv[pp], rv[pp], 0, 1, 2, 3);
      u16x4 hi = __builtin_shufflevector(rv[pp], rv[pp], 4, 5, 6, 7);
      *(u16x4*)&Vts[d * 128 + ((ch0 ^ (d & 15)) << 3) + of0] = lo;
      *(u16x4*)&Vts[d * 128 + ((ch1 ^ (d & 15)) << 3) + of0] = hi;
    }
    if (kt + 1 < 32) LOAD_TILE(kt + 1);
    __syncthreads();

    f32x4 s[8];
#pragma unroll
    for (int c = 0; c < 8; ++c) s[c] = z4;
#pragma unroll
    for (int kk = 0; kk < 2; ++kk)
#pragma unroll
      for (int c = 0; c < 8; ++c) {
        int row = c * 16 + lc;
        bf16x8 kf = *(const bf16x8*)&Ks[row * 64 + (((kk * 4 + g) ^ (row & 7)) << 3)];
        s[c] = __builtin_amdgcn_mfma_f32_16x16x32_bf16(kf, qf[kk], s[c], 0, 0, 0);
      }

    float mx = s[0][0];
#pragma unroll
    for (int c = 0; c < 8; ++c)
#pragma unroll
      for (int r = 0; r < 4; ++r) mx = fmaxf(mx, s[c][r]);
    mx = fmaxf(mx, __shfl_xor(mx, 16));
    mx = fmaxf(mx, __shfl_xor(mx, 32));
    float nm = fmaxf(mrun, mx);
    float al = __expf(mrun - nm);
    mrun = nm;
    float ls = 0.f;
#pragma unroll
    for (int c = 0; c < 8; ++c)
#pragma unroll
      for (int r = 0; r < 4; ++r) {
        float p = __expf(s[c][r] - nm);
        s[c][r] = p;
        ls += p;
      }
    ls += __shfl_xor(ls, 16);
    ls += __shfl_xor(ls, 32);
    lrun = lrun * al + ls;
#pragma unroll
    for (int df = 0; df < 4; ++df)
#pragma unroll
      for (int r = 0; r < 4; ++r) oacc[df][r] *= al;

    uint32_t pk[8][2];
#pragma unroll
    for (int c = 0; c < 8; ++c)
#pragma unroll
      for (int w2 = 0; w2 < 2; ++w2)
        pk[c][w2] = cvtpk(s[c][2 * w2], s[c][2 * w2 + 1]);

#pragma unroll
    for (int kb = 0; kb < 4; ++kb) {
      u32x4 pw = {pk[2 * kb][0], pk[2 * kb][1], pk[2 * kb + 1][0], pk[2 * kb + 1][1]};
      bf16x8 pa = __builtin_bit_cast(bf16x8, pw);
#pragma unroll
      for (int df = 0; df < 4; ++df) {
        int row = df * 16 + lc;
        bf16x8 vf = *(const bf16x8*)&Vts[row * 128 + (((kb * 4 + g) ^ (row & 15)) << 3)];
        oacc[df] = __builtin_amdgcn_mfma_f32_16x16x32_bf16(vf, pa, oacc[df], 0, 0, 0);
      }
    }
  }
#undef LOAD_TILE

  float inv = 1.0f / lrun;
#pragma unroll
  for (int df = 0; df < 4; ++df) {
    us4 wv{f2bf(oacc[df][0] * inv), f2bf(oacc[df][1] * inv),
           f2bf(oacc[df][2] * inv), f2bf(oacc[df][3] * inv)};
    *(us4*)&Ob[((size_t)b * NQ + qrow) * DIMF + h * 64 + df * 16 + g * 4] = wv;
  }
}

// ---------------- launch ----------------------------------------------------
extern "C" void kernel_launch(void* const* d_in, const int* in_sizes, int n_in,
                              void* d_out, int out_size, void* d_ws, size_t ws_size,
                              hipStream_t stream) {
  const float* x      = (const float*)d_in[0];
  const float* ctx    = (const float*)d_in[1];
  const float* rope_q = (const float*)d_in[2];
  const float* rope_k = (const float*)d_in[3];
  const float* Wq     = (const float*)d_in[4];
  const float* Wk     = (const float*)d_in[5];
  const float* Wv     = (const float*)d_in[6];
  const float* Wo     = (const float*)d_in[7];

  char* ws = (char*)d_ws;
  const size_t SZ_CTXB = (size_t)NB * NKV * DIMF * 2;
  const size_t SZ_XB   = (size_t)NB * NQ * DIMF * 2;
  const size_t SZ_WT   = (size_t)DIMF * DIMF * 2;
  unsigned short* ctxb = (unsigned short*)(ws);
  unsigned short* ob   = (unsigned short*)(ws);                       // alias ctxb (dead after V-GEMM)
  unsigned short* xb   = (unsigned short*)(ws + SZ_CTXB);
  unsigned short* wkt  = (unsigned short*)(ws + SZ_CTXB + SZ_XB);
  unsigned short* wvt  = (unsigned short*)(ws + SZ_CTXB + SZ_XB + SZ_WT);
  unsigned short* wqt  = (unsigned short*)(ws + SZ_CTXB + SZ_XB + 2 * SZ_WT);
  unsigned short* wot  = (unsigned short*)(ws + SZ_CTXB + SZ_XB + 3 * SZ_WT);
  unsigned short* kb   = (unsigned short*)(ws + SZ_CTXB + SZ_XB + 4 * SZ_WT);
  unsigned short* vtb  = (unsigned short*)(ws + SZ_CTXB + SZ_XB + 4 * SZ_WT + SZ_CTXB);
  unsigned short* qb   = (unsigned short*)(ws + SZ_CTXB + SZ_XB + 4 * SZ_WT + 2 * SZ_CTXB);

  cvt_kernel<<<dim3(2048), dim3(256), 0, stream>>>(ctx, ctxb, NB * NKV * DIMF);
  cvt_kernel<<<dim3(1024), dim3(256), 0, stream>>>(x, xb, NB * NQ * DIMF);
  twt_kernel<<<dim3(24, 24, 4), dim3(32, 8), 0, stream>>>(Wk, Wv, Wq, Wo, wkt, wvt, wqt, wot);

  kvpipe_kernel<0><<<dim3(3072), dim3(256), 0, stream>>>(ctxb, wkt, kb, rope_k);
  kvpipe_kernel<1><<<dim3(3072), dim3(256), 0, stream>>>(ctxb, wvt, vtb, nullptr);
  gemm_kernel<2><<<dim3(32, 6), dim3(256), 0, stream>>>(xb, wqt, qb, rope_q);

  attn_kernel<<<dim3(768), dim3(256), 0, stream>>>(qb, kb, vtb, ob);

  gemm_kernel<3><<<dim3(32, 6), dim3(256), 0, stream>>>(ob, wot, d_out, nullptr);
}

// Round 13
// 395.535 us; speedup vs baseline: 1.1471x; 1.1471x over previous
//
#include <hip/hip_runtime.h>
#include <stdint.h>

// ---------------------------------------------------------------------------
// CrossAttentionRope: x(16,256,768), ctx(16,4096,768) f32 -> out(16,256,768) f32
// R13: R8 base (best, 394us); the two KV GEMM dispatches merged into ONE
//      kernel over N=1536 (wkt|wvt are already contiguous = wkvt[1536][768]).
//      Per-block code verbatim R8 (128x128, 4 waves, reg-staged + XOR swz);
//      grid 6144, XCD col-fast swizzle -> each A panel's 12 col-blocks
//      adjacent on one XCD (A fetched from HBM once, not twice).
//      Block-uniform epilogue branch: colBase<768 -> K+rope, else V^T.
//      cvt/twt/Q/O/attn verbatim R8.
// ---------------------------------------------------------------------------

typedef __bf16 bf16x8 __attribute__((ext_vector_type(8)));
typedef unsigned short u16x8 __attribute__((ext_vector_type(8)));
typedef unsigned short u16x4 __attribute__((ext_vector_type(4)));
typedef uint32_t u32x4 __attribute__((ext_vector_type(4)));
typedef float f32x4 __attribute__((ext_vector_type(4)));

#define DIMF 768
#define NHEAD 12
#define NKV 4096
#define NQ 256
#define NB 16

struct alignas(8) us4 { unsigned short x, y, z, w; };

__device__ __forceinline__ unsigned short f2bf(float x) {
  uint32_t u = __float_as_uint(x);
  u += 0x7fffu + ((u >> 16) & 1u);   // round-to-nearest-even
  return (unsigned short)(u >> 16);
}

__device__ __forceinline__ uint32_t cvtpk(float a, float b) {
  uint32_t r;
  asm("v_cvt_pk_bf16_f32 %0, %1, %2" : "=v"(r) : "v"(a), "v"(b));
  return r;
}

// ---------------- convert f32 -> bf16 (vectorized, grid-stride) ------------
__global__ void cvt_kernel(const float* __restrict__ in, unsigned short* __restrict__ out, int n) {
  int stride = gridDim.x * blockDim.x * 4;
  for (int i = (blockIdx.x * blockDim.x + threadIdx.x) * 4; i < n; i += stride) {
    float4 v = *(const float4*)(in + i);
    us4 o{f2bf(v.x), f2bf(v.y), f2bf(v.z), f2bf(v.w)};
    *(us4*)(out + i) = o;
  }
}

// ---------------- weight transpose + cvt: Wt[n][k] = W[k][n] ---------------
__global__ void twt_kernel(const float* __restrict__ W0, const float* __restrict__ W1,
                           const float* __restrict__ W2, const float* __restrict__ W3,
                           unsigned short* __restrict__ O0, unsigned short* __restrict__ O1,
                           unsigned short* __restrict__ O2, unsigned short* __restrict__ O3) {
  const float* W; unsigned short* O;
  switch (blockIdx.z) {
    case 0: W = W0; O = O0; break;
    case 1: W = W1; O = O1; break;
    case 2: W = W2; O = O2; break;
    default: W = W3; O = O3; break;
  }
  __shared__ float t[32][33];
  int x0 = blockIdx.x * 32, y0 = blockIdx.y * 32;
  int tx = threadIdx.x, ty = threadIdx.y;
#pragma unroll
  for (int j = 0; j < 4; ++j)
    t[ty + 8 * j][tx] = W[(size_t)(y0 + ty + 8 * j) * DIMF + x0 + tx];
  __syncthreads();
#pragma unroll
  for (int j = 0; j < 4; ++j)
    O[(size_t)(x0 + ty + 8 * j) * DIMF + y0 + tx] = f2bf(t[tx][ty + 8 * j]);
}

// ---------------- merged KV GEMM: C(128x128 of 65536x1536) -------------------
// B = wkvt[1536][768] (wkt||wvt contiguous). Grid 6144 (512 rows x 12 cols),
// col-fast + bijective XCD swizzle. Per-block structure verbatim R8.
__launch_bounds__(256, 2)
__global__ void kvgemm_kernel(const unsigned short* __restrict__ A,
                              const unsigned short* __restrict__ Bkv,
                              unsigned short* __restrict__ Ko,
                              unsigned short* __restrict__ Vt,
                              const float* __restrict__ rope) {
  __shared__ unsigned short As[128 * 64];
  __shared__ unsigned short Bs[128 * 64];
  const int t = threadIdx.x;
  const int lane = t & 63, wid = t >> 6;
  const int g = lane >> 4, lc = lane & 15;
  const int wr = wid >> 1, wc = wid & 1;

  // 6144 % 8 == 0: bijective XCD remap; col (swz%12) fast so one A row-panel's
  // 12 col-blocks (6 K + 6 V) run adjacent on the same XCD.
  const int swz = (blockIdx.x & 7) * 768 + (blockIdx.x >> 3);
  const int rowBase = (swz / 12) * 128;
  const int colBase = (swz % 12) * 128;

  const f32x4 z4 = {0.f, 0.f, 0.f, 0.f};
  f32x4 acc[4][4];
#pragma unroll
  for (int m = 0; m < 4; ++m)
#pragma unroll
    for (int n = 0; n < 4; ++n) acc[m][n] = z4;

  const int r0 = t >> 3;
  const int c0 = t & 7;

  bf16x8 ra[4], rbx[4];
#pragma unroll
  for (int pp = 0; pp < 4; ++pp) {
    int row = pp * 32 + r0;
    ra[pp] = *(const bf16x8*)(A + (size_t)(rowBase + row) * DIMF + c0 * 8);
    rbx[pp] = *(const bf16x8*)(Bkv + (size_t)(colBase + row) * DIMF + c0 * 8);
  }

  for (int kb = 0; kb < 12; ++kb) {
    __syncthreads();
#pragma unroll
    for (int pp = 0; pp < 4; ++pp) {
      int row = pp * 32 + r0;
      int ph = ((c0 ^ (row & 7)) << 3);
      *(bf16x8*)&As[row * 64 + ph] = ra[pp];
      *(bf16x8*)&Bs[row * 64 + ph] = rbx[pp];
    }
    __syncthreads();
    if (kb + 1 < 12) {
      int kn = (kb + 1) * 64;
#pragma unroll
      for (int pp = 0; pp < 4; ++pp) {
        int row = pp * 32 + r0;
        ra[pp] = *(const bf16x8*)(A + (size_t)(rowBase + row) * DIMF + kn + c0 * 8);
        rbx[pp] = *(const bf16x8*)(Bkv + (size_t)(colBase + row) * DIMF + kn + c0 * 8);
      }
    }
#pragma unroll
    for (int kk = 0; kk < 2; ++kk) {
      bf16x8 af[4], bfr[4];
#pragma unroll
      for (int m = 0; m < 4; ++m) {
        int row = wr * 64 + m * 16 + lc;
        int ch = kk * 4 + g;
        af[m] = *(const bf16x8*)&As[row * 64 + (((ch ^ (row & 7))) << 3)];
      }
#pragma unroll
      for (int n = 0; n < 4; ++n) {
        int row = wc * 64 + n * 16 + lc;
        int ch = kk * 4 + g;
        bfr[n] = *(const bf16x8*)&Bs[row * 64 + (((ch ^ (row & 7))) << 3)];
      }
#pragma unroll
      for (int m = 0; m < 4; ++m)
#pragma unroll
        for (int n = 0; n < 4; ++n)
          acc[m][n] = __builtin_amdgcn_mfma_f32_16x16x32_bf16(af[m], bfr[n], acc[m][n], 0, 0, 0);
    }
  }

  // ---- epilogue (C/D: col=lc, row=g*4+r — proven); branch uniform/block ----
  if (colBase < 768) {   // K output + rope
#pragma unroll
    for (int m = 0; m < 4; ++m)
#pragma unroll
      for (int n = 0; n < 4; ++n)
#pragma unroll
        for (int r = 0; r < 4; ++r) {
          int p = rowBase + wr * 64 + m * 16 + g * 4 + r;
          int f = colBase + wc * 64 + n * 16 + lc;
          int d = f & 63, h = f >> 6;
          float v = acc[m][n][r];
          float vo = __shfl_xor(v, 1);
          int b = p >> 12, nkv = p & 4095;
          float sn = rope[nkv * 128 + d], cs = rope[nkv * 128 + 64 + d];
          float o = (d & 1) ? fmaf(vo, sn, v * cs) : fmaf(-vo, sn, v * cs);
          Ko[((size_t)(b * NHEAD + h) * NKV + nkv) * 64 + d] = f2bf(o);
        }
  } else {               // V output, transposed [b][h][d][nkv]
#pragma unroll
    for (int m = 0; m < 4; ++m)
#pragma unroll
      for (int n = 0; n < 4; ++n) {
        int p0 = rowBase + wr * 64 + m * 16 + g * 4;
        int b = p0 >> 12, nkv0 = p0 & 4095;
        int f = (colBase - 768) + wc * 64 + n * 16 + lc;
        int d = f & 63, h = f >> 6;
        us4 wv{f2bf(acc[m][n][0]), f2bf(acc[m][n][1]), f2bf(acc[m][n][2]), f2bf(acc[m][n][3])};
        *(us4*)&Vt[((size_t)(b * NHEAD + h) * 64 + d) * NKV + nkv0] = wv;
      }
  }
}

// ---------------- GEMM (R5/R8-proven reg-staged): Q-proj / O-proj -----------
// MODE 2: Q-proj (+rope_q, *0.125) -> Q [b][h][nq][64] bf16  [2D grid]
// MODE 3: O-proj -> out f32 [p][768]                          [2D grid]
template <int MODE>
__launch_bounds__(256, 2)
__global__ void gemm_kernel(const unsigned short* __restrict__ A,
                            const unsigned short* __restrict__ Bt,
                            void* __restrict__ outp,
                            const float* __restrict__ rope) {
  __shared__ unsigned short As[128 * 64];
  __shared__ unsigned short Bs[128 * 64];
  const int t = threadIdx.x;
  const int lane = t & 63, wid = t >> 6;
  const int g = lane >> 4, lc = lane & 15;
  const int wr = wid >> 1, wc = wid & 1;
  const int rowBase = blockIdx.x * 128, colBase = blockIdx.y * 128;

  const f32x4 z4 = {0.f, 0.f, 0.f, 0.f};
  f32x4 acc[4][4];
#pragma unroll
  for (int m = 0; m < 4; ++m)
#pragma unroll
    for (int n = 0; n < 4; ++n) acc[m][n] = z4;

  const int r0 = t >> 3;
  const int c0 = t & 7;

  bf16x8 ra[4], rbx[4];
#pragma unroll
  for (int pp = 0; pp < 4; ++pp) {
    int row = pp * 32 + r0;
    ra[pp] = *(const bf16x8*)(A + (size_t)(rowBase + row) * DIMF + c0 * 8);
    rbx[pp] = *(const bf16x8*)(Bt + (size_t)(colBase + row) * DIMF + c0 * 8);
  }

  for (int kb = 0; kb < 12; ++kb) {
    __syncthreads();
#pragma unroll
    for (int pp = 0; pp < 4; ++pp) {
      int row = pp * 32 + r0;
      int ph = ((c0 ^ (row & 7)) << 3);
      *(bf16x8*)&As[row * 64 + ph] = ra[pp];
      *(bf16x8*)&Bs[row * 64 + ph] = rbx[pp];
    }
    __syncthreads();
    if (kb + 1 < 12) {
      int kn = (kb + 1) * 64;
#pragma unroll
      for (int pp = 0; pp < 4; ++pp) {
        int row = pp * 32 + r0;
        ra[pp] = *(const bf16x8*)(A + (size_t)(rowBase + row) * DIMF + kn + c0 * 8);
        rbx[pp] = *(const bf16x8*)(Bt + (size_t)(colBase + row) * DIMF + kn + c0 * 8);
      }
    }
#pragma unroll
    for (int kk = 0; kk < 2; ++kk) {
      bf16x8 af[4], bfr[4];
#pragma unroll
      for (int m = 0; m < 4; ++m) {
        int row = wr * 64 + m * 16 + lc;
        int ch = kk * 4 + g;
        af[m] = *(const bf16x8*)&As[row * 64 + (((ch ^ (row & 7))) << 3)];
      }
#pragma unroll
      for (int n = 0; n < 4; ++n) {
        int row = wc * 64 + n * 16 + lc;
        int ch = kk * 4 + g;
        bfr[n] = *(const bf16x8*)&Bs[row * 64 + (((ch ^ (row & 7))) << 3)];
      }
#pragma unroll
      for (int m = 0; m < 4; ++m)
#pragma unroll
        for (int n = 0; n < 4; ++n)
          acc[m][n] = __builtin_amdgcn_mfma_f32_16x16x32_bf16(af[m], bfr[n], acc[m][n], 0, 0, 0);
    }
  }

  if (MODE == 2) {
    unsigned short* Ko = (unsigned short*)outp;
#pragma unroll
    for (int m = 0; m < 4; ++m)
#pragma unroll
      for (int n = 0; n < 4; ++n)
#pragma unroll
        for (int r = 0; r < 4; ++r) {
          int p = rowBase + wr * 64 + m * 16 + g * 4 + r;
          int f = colBase + wc * 64 + n * 16 + lc;
          int d = f & 63, h = f >> 6;
          float v = acc[m][n][r];
          float vo = __shfl_xor(v, 1);
          int b = p >> 8, nq = p & 255;
          float sn = rope[nq * 128 + d], cs = rope[nq * 128 + 64 + d];
          float o = (d & 1) ? fmaf(vo, sn, v * cs) : fmaf(-vo, sn, v * cs);
          Ko[((size_t)(b * NHEAD + h) * NQ + nq) * 64 + d] = f2bf(o * 0.125f);
        }
  } else {
    float* Co = (float*)outp;
#pragma unroll
    for (int m = 0; m < 4; ++m)
#pragma unroll
      for (int n = 0; n < 4; ++n)
#pragma unroll
        for (int r = 0; r < 4; ++r) {
          int p = rowBase + wr * 64 + m * 16 + g * 4 + r;
          int f = colBase + wc * 64 + n * 16 + lc;
          Co[(size_t)p * DIMF + f] = acc[m][n][r];
        }
  }
}

// ---------------- flash attention (R5-proven, verbatim) --------------------
__launch_bounds__(256, 2)
__global__ void attn_kernel(const unsigned short* __restrict__ Qb,
                            const unsigned short* __restrict__ Kb,
                            const unsigned short* __restrict__ Vtb,
                            unsigned short* __restrict__ Ob) {
  __shared__ unsigned short Ks[128 * 64];    // [kv][d]  16KB, chunk ^= (kv&7)
  __shared__ unsigned short Vts[64 * 128];   // [d][kv'] 16KB, chunk ^= (d&15)
  const int logical = (blockIdx.x & 7) * 96 + (blockIdx.x >> 3);  // 768%8==0
  const int qt = logical & 3, bh = logical >> 2;
  const int b = bh / NHEAD, h = bh % NHEAD;
  const int t = threadIdx.x;
  const int lane = t & 63, w = t >> 6;
  const int g = lane >> 4, lc = lane & 15;
  const int qrow = qt * 64 + w * 16 + lc;

  bf16x8 qf[2];
#pragma unroll
  for (int kk = 0; kk < 2; ++kk)
    qf[kk] = *(const bf16x8*)(Qb + ((size_t)bh * NQ + qrow) * 64 + kk * 32 + g * 8);

  const f32x4 z4 = {0.f, 0.f, 0.f, 0.f};
  f32x4 oacc[4];
#pragma unroll
  for (int df = 0; df < 4; ++df) oacc[df] = z4;
  float mrun = -1e30f, lrun = 0.f;

  const int r0 = t >> 3, c0 = t & 7;
  const int d0 = t >> 4, cv = t & 15;
  const int pbase = 32 * (cv >> 2) + 16 * (cv & 1) + 4 * ((cv >> 1) & 1);
  const int ch0 = pbase >> 3, of0 = pbase & 7;
  const int ch1 = (pbase + 8) >> 3;

  u16x8 rk[4], rv[4];
#define LOAD_TILE(KT)                                                                        \
  do {                                                                                       \
    const int kvb = (KT) * 128;                                                              \
    _Pragma("unroll")                                                                        \
    for (int pp = 0; pp < 4; ++pp)                                                           \
      rk[pp] = *(const u16x8*)(Kb + ((size_t)bh * NKV + kvb + pp * 32 + r0) * 64 + c0 * 8);  \
    _Pragma("unroll")                                                                        \
    for (int pp = 0; pp < 4; ++pp)                                                           \
      rv[pp] = *(const u16x8*)(Vtb + ((size_t)bh * 64 + pp * 16 + d0) * NKV + kvb + cv * 8); \
  } while (0)

  LOAD_TILE(0);

  for (int kt = 0; kt < 32; ++kt) {
    __syncthreads();
#pragma unroll
    for (int pp = 0; pp < 4; ++pp) {
      int row = pp * 32 + r0;
      *(u16x8*)&Ks[row * 64 + ((c0 ^ (row & 7)) << 3)] = rk[pp];
    }
#pragma unroll
    for (int pp = 0; pp < 4; ++pp) {
      int d = pp * 16 + d0;
      u16x4 lo = __builtin_shufflevector(rv[pp], rv[pp], 0, 1, 2, 3);
      u16x4 hi = __builtin_shufflevector(rv[pp], rv[pp], 4, 5, 6, 7);
      *(u16x4*)&Vts[d * 128 + ((ch0 ^ (d & 15)) << 3) + of0] = lo;
      *(u16x4*)&Vts[d * 128 + ((ch1 ^ (d & 15)) << 3) + of0] = hi;
    }
    if (kt + 1 < 32) LOAD_TILE(kt + 1);
    __syncthreads();

    f32x4 s[8];
#pragma unroll
    for (int c = 0; c < 8; ++c) s[c] = z4;
#pragma unroll
    for (int kk = 0; kk < 2; ++kk)
#pragma unroll
      for (int c = 0; c < 8; ++c) {
        int row = c * 16 + lc;
        bf16x8 kf = *(const bf16x8*)&Ks[row * 64 + (((kk * 4 + g) ^ (row & 7)) << 3)];
        s[c] = __builtin_amdgcn_mfma_f32_16x16x32_bf16(kf, qf[kk], s[c], 0, 0, 0);
      }

    float mx = s[0][0];
#pragma unroll
    for (int c = 0; c < 8; ++c)
#pragma unroll
      for (int r = 0; r < 4; ++r) mx = fmaxf(mx, s[c][r]);
    mx = fmaxf(mx, __shfl_xor(mx, 16));
    mx = fmaxf(mx, __shfl_xor(mx, 32));
    float nm = fmaxf(mrun, mx);
    float al = __expf(mrun - nm);
    mrun = nm;
    float ls = 0.f;
#pragma unroll
    for (int c = 0; c < 8; ++c)
#pragma unroll
      for (int r = 0; r < 4; ++r) {
        float p = __expf(s[c][r] - nm);
        s[c][r] = p;
        ls += p;
      }
    ls += __shfl_xor(ls, 16);
    ls += __shfl_xor(ls, 32);
    lrun = lrun * al + ls;
#pragma unroll
    for (int df = 0; df < 4; ++df)
#pragma unroll
      for (int r = 0; r < 4; ++r) oacc[df][r] *= al;

    uint32_t pk[8][2];
#pragma unroll
    for (int c = 0; c < 8; ++c)
#pragma unroll
      for (int w2 = 0; w2 < 2; ++w2)
        pk[c][w2] = cvtpk(s[c][2 * w2], s[c][2 * w2 + 1]);

#pragma unroll
    for (int kb = 0; kb < 4; ++kb) {
      u32x4 pw = {pk[2 * kb][0], pk[2 * kb][1], pk[2 * kb + 1][0], pk[2 * kb + 1][1]};
      bf16x8 pa = __builtin_bit_cast(bf16x8, pw);
#pragma unroll
      for (int df = 0; df < 4; ++df) {
        int row = df * 16 + lc;
        bf16x8 vf = *(const bf16x8*)&Vts[row * 128 + (((kb * 4 + g) ^ (row & 15)) << 3)];
        oacc[df] = __builtin_amdgcn_mfma_f32_16x16x32_bf16(vf, pa, oacc[df], 0, 0, 0);
      }
    }
  }
#undef LOAD_TILE

  float inv = 1.0f / lrun;
#pragma unroll
  for (int df = 0; df < 4; ++df) {
    us4 wv{f2bf(oacc[df][0] * inv), f2bf(oacc[df][1] * inv),
           f2bf(oacc[df][2] * inv), f2bf(oacc[df][3] * inv)};
    *(us4*)&Ob[((size_t)b * NQ + qrow) * DIMF + h * 64 + df * 16 + g * 4] = wv;
  }
}

// ---------------- launch ----------------------------------------------------
extern "C" void kernel_launch(void* const* d_in, const int* in_sizes, int n_in,
                              void* d_out, int out_size, void* d_ws, size_t ws_size,
                              hipStream_t stream) {
  const float* x      = (const float*)d_in[0];
  const float* ctx    = (const float*)d_in[1];
  const float* rope_q = (const float*)d_in[2];
  const float* rope_k = (const float*)d_in[3];
  const float* Wq     = (const float*)d_in[4];
  const float* Wk     = (const float*)d_in[5];
  const float* Wv     = (const float*)d_in[6];
  const float* Wo     = (const float*)d_in[7];

  char* ws = (char*)d_ws;
  const size_t SZ_CTXB = (size_t)NB * NKV * DIMF * 2;
  const size_t SZ_XB   = (size_t)NB * NQ * DIMF * 2;
  const size_t SZ_WT   = (size_t)DIMF * DIMF * 2;
  unsigned short* ctxb = (unsigned short*)(ws);
  unsigned short* ob   = (unsigned short*)(ws);                       // alias ctxb (dead after kvgemm)
  unsigned short* xb   = (unsigned short*)(ws + SZ_CTXB);
  unsigned short* wkt  = (unsigned short*)(ws + SZ_CTXB + SZ_XB);           // wkt||wvt = wkvt[1536][768]
  unsigned short* wvt  = (unsigned short*)(ws + SZ_CTXB + SZ_XB + SZ_WT);
  unsigned short* wqt  = (unsigned short*)(ws + SZ_CTXB + SZ_XB + 2 * SZ_WT);
  unsigned short* wot  = (unsigned short*)(ws + SZ_CTXB + SZ_XB + 3 * SZ_WT);
  unsigned short* kb   = (unsigned short*)(ws + SZ_CTXB + SZ_XB + 4 * SZ_WT);
  unsigned short* vtb  = (unsigned short*)(ws + SZ_CTXB + SZ_XB + 4 * SZ_WT + SZ_CTXB);
  unsigned short* qb   = (unsigned short*)(ws + SZ_CTXB + SZ_XB + 4 * SZ_WT + 2 * SZ_CTXB);

  cvt_kernel<<<dim3(2048), dim3(256), 0, stream>>>(ctx, ctxb, NB * NKV * DIMF);
  cvt_kernel<<<dim3(1024), dim3(256), 0, stream>>>(x, xb, NB * NQ * DIMF);
  twt_kernel<<<dim3(24, 24, 4), dim3(32, 8), 0, stream>>>(Wk, Wv, Wq, Wo, wkt, wvt, wqt, wot);

  kvgemm_kernel<<<dim3(6144), dim3(256), 0, stream>>>(ctxb, wkt, kb, vtb, rope_k);
  gemm_kernel<2><<<dim3(32, 6), dim3(256), 0, stream>>>(xb, wqt, qb, rope_q);

  attn_kernel<<<dim3(768), dim3(256), 0, stream>>>(qb, kb, vtb, ob);

  gemm_kernel<3><<<dim3(32, 6), dim3(256), 0, stream>>>(ob, wot, d_out, nullptr);
}

// Round 14
// 390.562 us; speedup vs baseline: 1.1617x; 1.0127x over previous
//
#include <hip/hip_runtime.h>
#include <stdint.h>

// ---------------------------------------------------------------------------
// CrossAttentionRope: x(16,256,768), ctx(16,4096,768) f32 -> out(16,256,768) f32
// R14: merged KV GEMM rewritten as 256x256 8-phase counted-vmcnt kernel
//      (m201 template, derived to closure):
//      - 8 waves (wr=wid>>2, wc=wid&3), INTERLEAVED map: m-frag row m*32+wr*16,
//        n-frag col n*64+wc*16 -> phase q=(ah=q>>1,bh=q&1) reads exactly one
//        A-half & one B-half: m in [4ah,4ah+4), n in [2bh,2bh+2), 16 MFMA.
//      - LDS 128KB dynamic: As[2dbuf][2half][128*64], Bs same.
//      - gld_lds16 + pre-swizzled source chunk (R11-proven) + XOR'd ds_read.
//      - stream: tile T phases issue [T+1:Bb, T+1:Ab, T+2:At, T+2:Bt] (each
//        slot's readers retired at the preceding barrier); boundary vmcnt(4),
//        vmcnt(0) only before the last tile. T5 setprio around MFMA.
//      cvt/twt/Q/O/attn verbatim R13 (R5-proven).
// ---------------------------------------------------------------------------

typedef __bf16 bf16x8 __attribute__((ext_vector_type(8)));
typedef unsigned short u16x8 __attribute__((ext_vector_type(8)));
typedef unsigned short u16x4 __attribute__((ext_vector_type(4)));
typedef uint32_t u32x4 __attribute__((ext_vector_type(4)));
typedef float f32x4 __attribute__((ext_vector_type(4)));

#define DIMF 768
#define NHEAD 12
#define NKV 4096
#define NQ 256
#define NB 16

struct alignas(8) us4 { unsigned short x, y, z, w; };

__device__ __forceinline__ unsigned short f2bf(float x) {
  uint32_t u = __float_as_uint(x);
  u += 0x7fffu + ((u >> 16) & 1u);   // round-to-nearest-even
  return (unsigned short)(u >> 16);
}

__device__ __forceinline__ uint32_t cvtpk(float a, float b) {
  uint32_t r;
  asm("v_cvt_pk_bf16_f32 %0, %1, %2" : "=v"(r) : "v"(a), "v"(b));
  return r;
}

__device__ __forceinline__ void gld_lds16(const unsigned short* g, unsigned short* l) {
  __builtin_amdgcn_global_load_lds(
      (const __attribute__((address_space(1))) uint32_t*)(uintptr_t)g,
      (__attribute__((address_space(3))) uint32_t*)(uintptr_t)l, 16, 0, 0);
}

// ---------------- convert f32 -> bf16 (vectorized, grid-stride) ------------
__global__ void cvt_kernel(const float* __restrict__ in, unsigned short* __restrict__ out, int n) {
  int stride = gridDim.x * blockDim.x * 4;
  for (int i = (blockIdx.x * blockDim.x + threadIdx.x) * 4; i < n; i += stride) {
    float4 v = *(const float4*)(in + i);
    us4 o{f2bf(v.x), f2bf(v.y), f2bf(v.z), f2bf(v.w)};
    *(us4*)(out + i) = o;
  }
}

// ---------------- weight transpose + cvt: Wt[n][k] = W[k][n] ---------------
__global__ void twt_kernel(const float* __restrict__ W0, const float* __restrict__ W1,
                           const float* __restrict__ W2, const float* __restrict__ W3,
                           unsigned short* __restrict__ O0, unsigned short* __restrict__ O1,
                           unsigned short* __restrict__ O2, unsigned short* __restrict__ O3) {
  const float* W; unsigned short* O;
  switch (blockIdx.z) {
    case 0: W = W0; O = O0; break;
    case 1: W = W1; O = O1; break;
    case 2: W = W2; O = O2; break;
    default: W = W3; O = O3; break;
  }
  __shared__ float t[32][33];
  int x0 = blockIdx.x * 32, y0 = blockIdx.y * 32;
  int tx = threadIdx.x, ty = threadIdx.y;
#pragma unroll
  for (int j = 0; j < 4; ++j)
    t[ty + 8 * j][tx] = W[(size_t)(y0 + ty + 8 * j) * DIMF + x0 + tx];
  __syncthreads();
#pragma unroll
  for (int j = 0; j < 4; ++j)
    O[(size_t)(x0 + ty + 8 * j) * DIMF + y0 + tx] = f2bf(t[tx][ty + 8 * j]);
}

// ---------------- merged KV GEMM: 256x256, 8-phase counted-vmcnt ------------
// C(256x256 of 65536x1536) = ctxb * wkvt^T. Grid 1536 (256 rows x 6 cols),
// col-fast XCD swizzle. 512 thr / 8 waves; per-wave C = 128x64 interleaved.
__launch_bounds__(512, 2)
__global__ void kv8_kernel(const unsigned short* __restrict__ A,
                           const unsigned short* __restrict__ Bkv,
                           unsigned short* __restrict__ Ko,
                           unsigned short* __restrict__ Vt,
                           const float* __restrict__ rope) {
  extern __shared__ unsigned short smem[];   // 65536 shorts = 128KB
  // As half-buf (d,h) at smem + (d*2+h)*8192 ; Bs at smem + 32768 + (d*2+h)*8192
  const int t = threadIdx.x;
  const int lane = t & 63, wid = t >> 6;
  const int g = lane >> 4, lc = lane & 15;
  const int wr = wid >> 2, wc = wid & 3;

  const int swz = (blockIdx.x & 7) * 192 + (blockIdx.x >> 3);  // 1536%8==0
  const int rowBase = (swz / 6) * 256;
  const int colBase = (swz % 6) * 256;

  f32x4 acc[8][4];
#pragma unroll
  for (int m = 0; m < 8; ++m)
#pragma unroll
    for (int n = 0; n < 4; ++n)
#pragma unroll
      for (int r = 0; r < 4; ++r) acc[m][n][r] = 0.f;

  // staging map (R11-proven): lane -> row l>>3 within 8-row group; source
  // chunk pre-XOR'd so LDS[row][slot s] holds global chunk s^(row&7).
  const int sr = lane >> 3;
  const int sc = (lane & 7) ^ sr;
  const unsigned short* Abase0 = A + (size_t)(rowBase + wid * 16 + sr) * DIMF + sc * 8;
  const unsigned short* Bbase0 = Bkv + (size_t)(colBase + wid * 16 + sr) * DIMF + sc * 8;

  // stage one half-tile (16KB): 2 gld_lds16 per thread (wave covers 16 rows)
#define STAGE_A(T, h)                                                              \
  do {                                                                             \
    unsigned short* _lb = smem + (((T) & 1) * 2 + (h)) * 8192;                     \
    const unsigned short* _gb = Abase0 + (size_t)(h) * 128 * DIMF + (T) * 64;      \
    gld_lds16(_gb, _lb + (wid * 16) * 64);                                         \
    gld_lds16(_gb + (size_t)8 * DIMF, _lb + (wid * 16 + 8) * 64);                  \
  } while (0)
#define STAGE_B(T, h)                                                              \
  do {                                                                             \
    unsigned short* _lb = smem + 32768 + (((T) & 1) * 2 + (h)) * 8192;             \
    const unsigned short* _gb = Bbase0 + (size_t)(h) * 128 * DIMF + (T) * 64;      \
    gld_lds16(_gb, _lb + (wid * 16) * 64);                                         \
    gld_lds16(_gb + (size_t)8 * DIMF, _lb + (wid * 16 + 8) * 64);                  \
  } while (0)

  // prologue: T0 complete + T1's (A-top, B-top)  [6 halves, 12 loads/wave]
  STAGE_A(0, 0); STAGE_B(0, 0); STAGE_B(0, 1); STAGE_A(0, 1);
  STAGE_A(1, 0); STAGE_B(1, 0);

  bf16x8 af[4][2], bfr[2][2];

  for (int T = 0; T < 12; ++T) {
    const int dbuf = T & 1;
    // boundary: own tile-T halves landed; T+2's (At,Bt) stay in flight (T4)
    if (T == 11) asm volatile("s_waitcnt vmcnt(0)" ::: "memory");
    else         asm volatile("s_waitcnt vmcnt(4)" ::: "memory");
    asm volatile("" ::: "memory");
    __builtin_amdgcn_s_barrier();     // all waves' tile-T loads visible
    asm volatile("" ::: "memory");

#pragma unroll
    for (int q = 0; q < 4; ++q) {
      const int ah = q >> 1, bh = q & 1;
      const unsigned short* Ab = smem + (dbuf * 2 + ah) * 8192;
      const unsigned short* Bb = smem + 32768 + (dbuf * 2 + bh) * 8192;
      if ((q & 1) == 0) {            // A-half frags reused across 2 phases
#pragma unroll
        for (int mp = 0; mp < 4; ++mp)
#pragma unroll
          for (int kk = 0; kk < 2; ++kk) {
            int row = mp * 32 + wr * 16 + lc;
            af[mp][kk] = *(const bf16x8*)&Ab[row * 64 + (((kk * 4 + g) ^ (row & 7)) << 3)];
          }
      }
#pragma unroll
      for (int np = 0; np < 2; ++np)
#pragma unroll
        for (int kk = 0; kk < 2; ++kk) {
          int row = np * 64 + wc * 16 + lc;
          bfr[np][kk] = *(const bf16x8*)&Bb[row * 64 + (((kk * 4 + g) ^ (row & 7)) << 3)];
        }
      // stage issue (slot's readers retired at the preceding barrier):
      if (q == 0)      { if (T + 1 < 12) STAGE_B(T + 1, 1); }   // T+1:B-bot
      else if (q == 1) { if (T + 1 < 12) STAGE_A(T + 1, 1); }   // T+1:A-bot
      else if (q == 2) { if (T + 2 < 12) STAGE_A(T + 2, 0); }   // T+2:A-top (A-top retired ph1)
      else             { if (T + 2 < 12) STAGE_B(T + 2, 0); }   // T+2:B-top (B-top retired ph2)
      asm volatile("" ::: "memory");
      __builtin_amdgcn_s_barrier();
      asm volatile("s_waitcnt lgkmcnt(0)" ::: "memory");
      __builtin_amdgcn_s_setprio(1);
#pragma unroll
      for (int mp = 0; mp < 4; ++mp)
#pragma unroll
        for (int np = 0; np < 2; ++np)
#pragma unroll
          for (int kk = 0; kk < 2; ++kk)
            acc[4 * ah + mp][2 * bh + np] = __builtin_amdgcn_mfma_f32_16x16x32_bf16(
                af[mp][kk], bfr[np][kk], acc[4 * ah + mp][2 * bh + np], 0, 0, 0);
      __builtin_amdgcn_s_setprio(0);
      asm volatile("" ::: "memory");
      __builtin_amdgcn_s_barrier();
    }
  }
#undef STAGE_A
#undef STAGE_B

  // ---- epilogue (C/D: col=lc, row=g*4+r — proven); block-uniform branch ----
  // p = rowBase + m*32 + wr*16 + g*4 + r ; f = colBase + n*64 + wc*16 + lc
  if (colBase < 768) {   // K output + rope
#pragma unroll
    for (int m = 0; m < 8; ++m)
#pragma unroll
      for (int n = 0; n < 4; ++n)
#pragma unroll
        for (int r = 0; r < 4; ++r) {
          int p = rowBase + m * 32 + wr * 16 + g * 4 + r;
          int f = colBase + n * 64 + wc * 16 + lc;
          int d = f & 63, h = f >> 6;
          float v = acc[m][n][r];
          float vo = __shfl_xor(v, 1);
          int b = p >> 12, nkv = p & 4095;
          float sn = rope[nkv * 128 + d], cs = rope[nkv * 128 + 64 + d];
          float o = (d & 1) ? fmaf(vo, sn, v * cs) : fmaf(-vo, sn, v * cs);
          Ko[((size_t)(b * NHEAD + h) * NKV + nkv) * 64 + d] = f2bf(o);
        }
  } else {               // V output, transposed [b][h][d][nkv]
#pragma unroll
    for (int m = 0; m < 8; ++m)
#pragma unroll
      for (int n = 0; n < 4; ++n) {
        int p0 = rowBase + m * 32 + wr * 16 + g * 4;
        int b = p0 >> 12, nkv0 = p0 & 4095;
        int f = (colBase - 768) + n * 64 + wc * 16 + lc;
        int d = f & 63, h = f >> 6;
        us4 wv{f2bf(acc[m][n][0]), f2bf(acc[m][n][1]), f2bf(acc[m][n][2]), f2bf(acc[m][n][3])};
        *(us4*)&Vt[((size_t)(b * NHEAD + h) * 64 + d) * NKV + nkv0] = wv;
      }
  }
}

// ---------------- GEMM (R5/R8-proven reg-staged): Q-proj / O-proj -----------
// MODE 2: Q-proj (+rope_q, *0.125) -> Q [b][h][nq][64] bf16  [2D grid]
// MODE 3: O-proj -> out f32 [p][768]                          [2D grid]
template <int MODE>
__launch_bounds__(256, 2)
__global__ void gemm_kernel(const unsigned short* __restrict__ A,
                            const unsigned short* __restrict__ Bt,
                            void* __restrict__ outp,
                            const float* __restrict__ rope) {
  __shared__ unsigned short As[128 * 64];
  __shared__ unsigned short Bs[128 * 64];
  const int t = threadIdx.x;
  const int lane = t & 63, wid = t >> 6;
  const int g = lane >> 4, lc = lane & 15;
  const int wr = wid >> 1, wc = wid & 1;
  const int rowBase = blockIdx.x * 128, colBase = blockIdx.y * 128;

  const f32x4 z4 = {0.f, 0.f, 0.f, 0.f};
  f32x4 acc[4][4];
#pragma unroll
  for (int m = 0; m < 4; ++m)
#pragma unroll
    for (int n = 0; n < 4; ++n) acc[m][n] = z4;

  const int r0 = t >> 3;
  const int c0 = t & 7;

  bf16x8 ra[4], rbx[4];
#pragma unroll
  for (int pp = 0; pp < 4; ++pp) {
    int row = pp * 32 + r0;
    ra[pp] = *(const bf16x8*)(A + (size_t)(rowBase + row) * DIMF + c0 * 8);
    rbx[pp] = *(const bf16x8*)(Bt + (size_t)(colBase + row) * DIMF + c0 * 8);
  }

  for (int kb = 0; kb < 12; ++kb) {
    __syncthreads();
#pragma unroll
    for (int pp = 0; pp < 4; ++pp) {
      int row = pp * 32 + r0;
      int ph = ((c0 ^ (row & 7)) << 3);
      *(bf16x8*)&As[row * 64 + ph] = ra[pp];
      *(bf16x8*)&Bs[row * 64 + ph] = rbx[pp];
    }
    __syncthreads();
    if (kb + 1 < 12) {
      int kn = (kb + 1) * 64;
#pragma unroll
      for (int pp = 0; pp < 4; ++pp) {
        int row = pp * 32 + r0;
        ra[pp] = *(const bf16x8*)(A + (size_t)(rowBase + row) * DIMF + kn + c0 * 8);
        rbx[pp] = *(const bf16x8*)(Bt + (size_t)(colBase + row) * DIMF + kn + c0 * 8);
      }
    }
#pragma unroll
    for (int kk = 0; kk < 2; ++kk) {
      bf16x8 af[4], bfr[4];
#pragma unroll
      for (int m = 0; m < 4; ++m) {
        int row = wr * 64 + m * 16 + lc;
        int ch = kk * 4 + g;
        af[m] = *(const bf16x8*)&As[row * 64 + (((ch ^ (row & 7))) << 3)];
      }
#pragma unroll
      for (int n = 0; n < 4; ++n) {
        int row = wc * 64 + n * 16 + lc;
        int ch = kk * 4 + g;
        bfr[n] = *(const bf16x8*)&Bs[row * 64 + (((ch ^ (row & 7))) << 3)];
      }
#pragma unroll
      for (int m = 0; m < 4; ++m)
#pragma unroll
        for (int n = 0; n < 4; ++n)
          acc[m][n] = __builtin_amdgcn_mfma_f32_16x16x32_bf16(af[m], bfr[n], acc[m][n], 0, 0, 0);
    }
  }

  if (MODE == 2) {
    unsigned short* Ko = (unsigned short*)outp;
#pragma unroll
    for (int m = 0; m < 4; ++m)
#pragma unroll
      for (int n = 0; n < 4; ++n)
#pragma unroll
        for (int r = 0; r < 4; ++r) {
          int p = rowBase + wr * 64 + m * 16 + g * 4 + r;
          int f = colBase + wc * 64 + n * 16 + lc;
          int d = f & 63, h = f >> 6;
          float v = acc[m][n][r];
          float vo = __shfl_xor(v, 1);
          int b = p >> 8, nq = p & 255;
          float sn = rope[nq * 128 + d], cs = rope[nq * 128 + 64 + d];
          float o = (d & 1) ? fmaf(vo, sn, v * cs) : fmaf(-vo, sn, v * cs);
          Ko[((size_t)(b * NHEAD + h) * NQ + nq) * 64 + d] = f2bf(o * 0.125f);
        }
  } else {
    float* Co = (float*)outp;
#pragma unroll
    for (int m = 0; m < 4; ++m)
#pragma unroll
      for (int n = 0; n < 4; ++n)
#pragma unroll
        for (int r = 0; r < 4; ++r) {
          int p = rowBase + wr * 64 + m * 16 + g * 4 + r;
          int f = colBase + wc * 64 + n * 16 + lc;
          Co[(size_t)p * DIMF + f] = acc[m][n][r];
        }
  }
}

// ---------------- flash attention (R5-proven, verbatim) --------------------
__launch_bounds__(256, 2)
__global__ void attn_kernel(const unsigned short* __restrict__ Qb,
                            const unsigned short* __restrict__ Kb,
                            const unsigned short* __restrict__ Vtb,
                            unsigned short* __restrict__ Ob) {
  __shared__ unsigned short Ks[128 * 64];    // [kv][d]  16KB, chunk ^= (kv&7)
  __shared__ unsigned short Vts[64 * 128];   // [d][kv'] 16KB, chunk ^= (d&15)
  const int logical = (blockIdx.x & 7) * 96 + (blockIdx.x >> 3);  // 768%8==0
  const int qt = logical & 3, bh = logical >> 2;
  const int b = bh / NHEAD, h = bh % NHEAD;
  const int t = threadIdx.x;
  const int lane = t & 63, w = t >> 6;
  const int g = lane >> 4, lc = lane & 15;
  const int qrow = qt * 64 + w * 16 + lc;

  bf16x8 qf[2];
#pragma unroll
  for (int kk = 0; kk < 2; ++kk)
    qf[kk] = *(const bf16x8*)(Qb + ((size_t)bh * NQ + qrow) * 64 + kk * 32 + g * 8);

  const f32x4 z4 = {0.f, 0.f, 0.f, 0.f};
  f32x4 oacc[4];
#pragma unroll
  for (int df = 0; df < 4; ++df) oacc[df] = z4;
  float mrun = -1e30f, lrun = 0.f;

  const int r0 = t >> 3, c0 = t & 7;
  const int d0 = t >> 4, cv = t & 15;
  const int pbase = 32 * (cv >> 2) + 16 * (cv & 1) + 4 * ((cv >> 1) & 1);
  const int ch0 = pbase >> 3, of0 = pbase & 7;
  const int ch1 = (pbase + 8) >> 3;

  u16x8 rk[4], rv[4];
#define LOAD_TILE(KT)                                                                        \
  do {                                                                                       \
    const int kvb = (KT) * 128;                                                              \
    _Pragma("unroll")                                                                        \
    for (int pp = 0; pp < 4; ++pp)                                                           \
      rk[pp] = *(const u16x8*)(Kb + ((size_t)bh * NKV + kvb + pp * 32 + r0) * 64 + c0 * 8);  \
    _Pragma("unroll")                                                                        \
    for (int pp = 0; pp < 4; ++pp)                                                           \
      rv[pp] = *(const u16x8*)(Vtb + ((size_t)bh * 64 + pp * 16 + d0) * NKV + kvb + cv * 8); \
  } while (0)

  LOAD_TILE(0);

  for (int kt = 0; kt < 32; ++kt) {
    __syncthreads();
#pragma unroll
    for (int pp = 0; pp < 4; ++pp) {
      int row = pp * 32 + r0;
      *(u16x8*)&Ks[row * 64 + ((c0 ^ (row & 7)) << 3)] = rk[pp];
    }
#pragma unroll
    for (int pp = 0; pp < 4; ++pp) {
      int d = pp * 16 + d0;
      u16x4 lo = __builtin_shufflevector(rv[pp], rv[pp], 0, 1, 2, 3);
      u16x4 hi = __builtin_shufflevector(rv[pp], rv[pp], 4, 5, 6, 7);
      *(u16x4*)&Vts[d * 128 + ((ch0 ^ (d & 15)) << 3) + of0] = lo;
      *(u16x4*)&Vts[d * 128 + ((ch1 ^ (d & 15)) << 3) + of0] = hi;
    }
    if (kt + 1 < 32) LOAD_TILE(kt + 1);
    __syncthreads();

    f32x4 s[8];
#pragma unroll
    for (int c = 0; c < 8; ++c) s[c] = z4;
#pragma unroll
    for (int kk = 0; kk < 2; ++kk)
#pragma unroll
      for (int c = 0; c < 8; ++c) {
        int row = c * 16 + lc;
        bf16x8 kf = *(const bf16x8*)&Ks[row * 64 + (((kk * 4 + g) ^ (row & 7)) << 3)];
        s[c] = __builtin_amdgcn_mfma_f32_16x16x32_bf16(kf, qf[kk], s[c], 0, 0, 0);
      }

    float mx = s[0][0];
#pragma unroll
    for (int c = 0; c < 8; ++c)
#pragma unroll
      for (int r = 0; r < 4; ++r) mx = fmaxf(mx, s[c][r]);
    mx = fmaxf(mx, __shfl_xor(mx, 16));
    mx = fmaxf(mx, __shfl_xor(mx, 32));
    float nm = fmaxf(mrun, mx);
    float al = __expf(mrun - nm);
    mrun = nm;
    float ls = 0.f;
#pragma unroll
    for (int c = 0; c < 8; ++c)
#pragma unroll
      for (int r = 0; r < 4; ++r) {
        float p = __expf(s[c][r] - nm);
        s[c][r] = p;
        ls += p;
      }
    ls += __shfl_xor(ls, 16);
    ls += __shfl_xor(ls, 32);
    lrun = lrun * al + ls;
#pragma unroll
    for (int df = 0; df < 4; ++df)
#pragma unroll
      for (int r = 0; r < 4; ++r) oacc[df][r] *= al;

    uint32_t pk[8][2];
#pragma unroll
    for (int c = 0; c < 8; ++c)
#pragma unroll
      for (int w2 = 0; w2 < 2; ++w2)
        pk[c][w2] = cvtpk(s[c][2 * w2], s[c][2 * w2 + 1]);

#pragma unroll
    for (int kb = 0; kb < 4; ++kb) {
      u32x4 pw = {pk[2 * kb][0], pk[2 * kb][1], pk[2 * kb + 1][0], pk[2 * kb + 1][1]};
      bf16x8 pa = __builtin_bit_cast(bf16x8, pw);
#pragma unroll
      for (int df = 0; df < 4; ++df) {
        int row = df * 16 + lc;
        bf16x8 vf = *(const bf16x8*)&Vts[row * 128 + (((kb * 4 + g) ^ (row & 15)) << 3)];
        oacc[df] = __builtin_amdgcn_mfma_f32_16x16x32_bf16(vf, pa, oacc[df], 0, 0, 0);
      }
    }
  }
#undef LOAD_TILE

  float inv = 1.0f / lrun;
#pragma unroll
  for (int df = 0; df < 4; ++df) {
    us4 wv{f2bf(oacc[df][0] * inv), f2bf(oacc[df][1] * inv),
           f2bf(oacc[df][2] * inv), f2bf(oacc[df][3] * inv)};
    *(us4*)&Ob[((size_t)b * NQ + qrow) * DIMF + h * 64 + df * 16 + g * 4] = wv;
  }
}

// ---------------- launch ----------------------------------------------------
extern "C" void kernel_launch(void* const* d_in, const int* in_sizes, int n_in,
                              void* d_out, int out_size, void* d_ws, size_t ws_size,
                              hipStream_t stream) {
  const float* x      = (const float*)d_in[0];
  const float* ctx    = (const float*)d_in[1];
  const float* rope_q = (const float*)d_in[2];
  const float* rope_k = (const float*)d_in[3];
  const float* Wq     = (const float*)d_in[4];
  const float* Wk     = (const float*)d_in[5];
  const float* Wv     = (const float*)d_in[6];
  const float* Wo     = (const float*)d_in[7];

  char* ws = (char*)d_ws;
  const size_t SZ_CTXB = (size_t)NB * NKV * DIMF * 2;
  const size_t SZ_XB   = (size_t)NB * NQ * DIMF * 2;
  const size_t SZ_WT   = (size_t)DIMF * DIMF * 2;
  unsigned short* ctxb = (unsigned short*)(ws);
  unsigned short* ob   = (unsigned short*)(ws);                       // alias ctxb (dead after kvgemm)
  unsigned short* xb   = (unsigned short*)(ws + SZ_CTXB);
  unsigned short* wkt  = (unsigned short*)(ws + SZ_CTXB + SZ_XB);           // wkt||wvt = wkvt[1536][768]
  unsigned short* wvt  = (unsigned short*)(ws + SZ_CTXB + SZ_XB + SZ_WT);
  unsigned short* wqt  = (unsigned short*)(ws + SZ_CTXB + SZ_XB + 2 * SZ_WT);
  unsigned short* wot  = (unsigned short*)(ws + SZ_CTXB + SZ_XB + 3 * SZ_WT);
  unsigned short* kb   = (unsigned short*)(ws + SZ_CTXB + SZ_XB + 4 * SZ_WT);
  unsigned short* vtb  = (unsigned short*)(ws + SZ_CTXB + SZ_XB + 4 * SZ_WT + SZ_CTXB);
  unsigned short* qb   = (unsigned short*)(ws + SZ_CTXB + SZ_XB + 4 * SZ_WT + 2 * SZ_CTXB);

  cvt_kernel<<<dim3(2048), dim3(256), 0, stream>>>(ctx, ctxb, NB * NKV * DIMF);
  cvt_kernel<<<dim3(1024), dim3(256), 0, stream>>>(x, xb, NB * NQ * DIMF);
  twt_kernel<<<dim3(24, 24, 4), dim3(32, 8), 0, stream>>>(Wk, Wv, Wq, Wo, wkt, wvt, wqt, wot);

  kv8_kernel<<<dim3(1536), dim3(512), 131072, stream>>>(ctxb, wkt, kb, vtb, rope_k);
  gemm_kernel<2><<<dim3(32, 6), dim3(256), 0, stream>>>(xb, wqt, qb, rope_q);

  attn_kernel<<<dim3(768), dim3(256), 0, stream>>>(qb, kb, vtb, ob);

  gemm_kernel<3><<<dim3(32, 6), dim3(256), 0, stream>>>(ob, wot, d_out, nullptr);
}